// Round 1
// baseline (928.927 us; speedup 1.0000x reference)
//
#include <hip/hip_runtime.h>
#include <hip/hip_bf16.h>

// Problem: single-head causal attention
//   x[512,256,384] fp32, w_qkv[384,192] fp32
//   qkv = x @ w_qkv ; q,k,v = split(qkv) each [B,T,64]
//   out = softmax_causal(q k^T / sqrt(384)) @ v   -> [512,256,64] fp32
//
// Round 0: correctness-first fp32. Two kernels:
//   1) proj_kernel : GEMM [BT=131072, 384] x [384, 192] -> ws planes Q,K,V
//   2) attn_kernel : one block per batch; per-thread online softmax,
//                    K/V chunked through LDS (broadcast reads).

constexpr int B  = 512;
constexpr int T  = 256;
constexpr int C  = 384;
constexpr int HS = 64;             // head size
constexpr long BT = (long)B * T;   // 131072
constexpr long PLANE = BT * HS;    // 8,388,608 floats per Q/K/V plane
constexpr float SCALE = 0.05103103630798288f; // 1/sqrt(384)

constexpr int PROJ_ROWS = 8;

__global__ __launch_bounds__(192)
void proj_kernel(const float* __restrict__ x, const float* __restrict__ w,
                 float* __restrict__ qkv /* 3 planes of BT*64 */) {
    __shared__ float xs[PROJ_ROWS * C];   // 12 KB
    const int tid = threadIdx.x;          // 0..191, one output column each
    const long row0 = (long)blockIdx.x * PROJ_ROWS;

    // Stage 8 consecutive x rows (8*384 = 3072 floats = 768 float4)
    const float4* xsrc = (const float4*)(x + row0 * C);
    float4* xdst = (float4*)xs;
#pragma unroll
    for (int i = 0; i < 4; ++i) xdst[tid + i * 192] = xsrc[tid + i * 192];
    __syncthreads();

    float acc[PROJ_ROWS];
#pragma unroll
    for (int r = 0; r < PROJ_ROWS; ++r) acc[r] = 0.f;

    for (int c4 = 0; c4 < C; c4 += 4) {
        const float wv0 = w[(c4 + 0) * 192 + tid];
        const float wv1 = w[(c4 + 1) * 192 + tid];
        const float wv2 = w[(c4 + 2) * 192 + tid];
        const float wv3 = w[(c4 + 3) * 192 + tid];
#pragma unroll
        for (int r = 0; r < PROJ_ROWS; ++r) {
            const float4 xv = *(const float4*)(&xs[r * C + c4]);
            acc[r] += xv.x * wv0 + xv.y * wv1 + xv.z * wv2 + xv.w * wv3;
        }
    }

    const int plane = tid >> 6;   // 0=Q 1=K 2=V
    const int dd    = tid & 63;
    float* outp = qkv + (long)plane * PLANE;
#pragma unroll
    for (int r = 0; r < PROJ_ROWS; ++r)
        outp[(row0 + r) * HS + dd] = acc[r];
}

__global__ __launch_bounds__(256)
void attn_kernel(const float* __restrict__ qkv, float* __restrict__ out) {
    __shared__ float Ks[64 * HS];   // 16 KB
    __shared__ float Vs[64 * HS];   // 16 KB

    const int b = blockIdx.x;
    const int t = threadIdx.x;          // query index 0..255
    const int wave = t >> 6;            // 0..3

    const float* Q = qkv + 0 * PLANE + (long)b * T * HS;
    const float* K = qkv + 1 * PLANE + (long)b * T * HS;
    const float* V = qkv + 2 * PLANE + (long)b * T * HS;

    // q row into registers
    float q[HS];
#pragma unroll
    for (int d = 0; d < HS; d += 4) {
        const float4 v4 = *(const float4*)(Q + (long)t * HS + d);
        q[d] = v4.x; q[d + 1] = v4.y; q[d + 2] = v4.z; q[d + 3] = v4.w;
    }

    float o[HS];
#pragma unroll
    for (int d = 0; d < HS; ++d) o[d] = 0.f;
    float l = 0.f;

    for (int c = 0; c < 4; ++c) {       // key chunks of 64
        __syncthreads();                // protect previous chunk's readers
        // stage K/V chunk: 4096 floats each = 1024 float4; 256 thr x 4
        {
            const float4* ksrc = (const float4*)(K + (long)c * 64 * HS);
            const float4* vsrc = (const float4*)(V + (long)c * 64 * HS);
            float4* kdst = (float4*)Ks;
            float4* vdst = (float4*)Vs;
#pragma unroll
            for (int i = 0; i < 4; ++i) {
                kdst[t + i * 256] = ksrc[t + i * 256];
                vdst[t + i * 256] = vsrc[t + i * 256];
            }
        }
        __syncthreads();

        if (c <= wave) {                // wave-uniform branch
            const int jmax = min(64, t - c * 64 + 1);  // causal bound
            for (int j = 0; j < jmax; ++j) {
                float s = 0.f;
#pragma unroll
                for (int d = 0; d < HS; d += 4) {
                    const float4 kv = *(const float4*)(&Ks[j * HS + d]);
                    s += q[d] * kv.x + q[d + 1] * kv.y
                       + q[d + 2] * kv.z + q[d + 3] * kv.w;
                }
                // scores ~ N(0, 0.41^2): exp without max-shift is safe in fp32
                const float p = __expf(s * SCALE);
                l += p;
#pragma unroll
                for (int d = 0; d < HS; d += 4) {
                    const float4 vv = *(const float4*)(&Vs[j * HS + d]);
                    o[d]     += p * vv.x;
                    o[d + 1] += p * vv.y;
                    o[d + 2] += p * vv.z;
                    o[d + 3] += p * vv.w;
                }
            }
        }
    }

    const float inv_l = 1.0f / l;
    float* op = out + ((long)b * T + t) * HS;
#pragma unroll
    for (int d = 0; d < HS; d += 4) {
        float4 v4;
        v4.x = o[d] * inv_l;  v4.y = o[d + 1] * inv_l;
        v4.z = o[d + 2] * inv_l;  v4.w = o[d + 3] * inv_l;
        *(float4*)(op + d) = v4;
    }
}

extern "C" void kernel_launch(void* const* d_in, const int* in_sizes, int n_in,
                              void* d_out, int out_size, void* d_ws, size_t ws_size,
                              hipStream_t stream) {
    const float* x = (const float*)d_in[0];      // [512,256,384]
    const float* w = (const float*)d_in[1];      // [384,192]
    float* out = (float*)d_out;                  // [512,256,64]
    float* qkv = (float*)d_ws;                   // 3 * 8,388,608 floats = 96 MB

    proj_kernel<<<dim3((unsigned)(BT / PROJ_ROWS)), dim3(192), 0, stream>>>(x, w, qkv);
    attn_kernel<<<dim3(B), dim3(T), 0, stream>>>(qkv, out);
}

// Round 2
// 589.521 us; speedup vs baseline: 1.5757x; 1.5757x over previous
//
#include <hip/hip_runtime.h>
#include <hip/hip_bf16.h>

// Single-head causal attention: x[512,256,384] fp32, w_qkv[384,192] fp32
//   qkv = x @ w_qkv ; out = softmax_causal(q k^T / sqrt(384)) @ v -> [512,256,64] fp32
//
// Round 2: projection as bf16 MFMA GEMM (16x16x32), fp32 accumulate.
//   wt_kernel   : pack W^T into bf16 [192][384] (one-time, L2-resident)
//   proj_kernel : 128x192 block tile, 4 waves (2x2), wave=64x96=4x6 subtiles,
//                 BK=64 LDS chunks, +8-short row pad (2-way bank alias = free)
//   attn_kernel : unchanged fp32 (next round's target)

constexpr int B  = 512;
constexpr int T  = 256;
constexpr int C  = 384;
constexpr int HS = 64;
constexpr long BT = (long)B * T;     // 131072
constexpr long PLANE = BT * HS;      // 8,388,608 floats per plane
constexpr float SCALE = 0.05103103630798288f; // 1/sqrt(384)

constexpr int NT   = 192;            // full N per block
constexpr int MT   = 128;            // rows per block
constexpr int BK   = 64;             // K chunk
constexpr int ROWP = BK + 8;         // padded LDS row (shorts); 144 B, 16B-aligned

typedef short bf16x8 __attribute__((ext_vector_type(8)));
typedef float f32x4  __attribute__((ext_vector_type(4)));

__device__ __forceinline__ unsigned short f2bf(float f) {
    union { float f; unsigned int u; } cv; cv.f = f;
    unsigned int b = cv.u;
    return (unsigned short)((b + 0x7FFFu + ((b >> 16) & 1u)) >> 16);  // RNE
}
__device__ __forceinline__ unsigned int pack2(float a, float b) {
    return (unsigned int)f2bf(a) | ((unsigned int)f2bf(b) << 16);
}

__global__ __launch_bounds__(256)
void wt_kernel(const float* __restrict__ w, short* __restrict__ wt) {
    const int idx = blockIdx.x * 256 + threadIdx.x;   // 0..73727
    if (idx < NT * C) {
        const int n = idx / C, k = idx % C;
        wt[idx] = (short)f2bf(w[k * NT + n]);         // wt[n][k] = w[k][n]
    }
}

__global__ __launch_bounds__(256, 2)
void proj_kernel(const float* __restrict__ x, const short* __restrict__ wt,
                 float* __restrict__ qkv) {
    __shared__ short XL[MT * ROWP];   // 128x72 shorts = 18.4 KB
    __shared__ short WL[NT * ROWP];   // 192x72 shorts = 27.6 KB

    const int tid  = threadIdx.x;
    const int lane = tid & 63;
    const int wv   = tid >> 6;        // wave 0..3
    const int wm   = wv >> 1;         // 0..1  (m half: 64 rows)
    const int wn   = wv & 1;          // 0..1  (n half: 96 cols)
    const int l15  = lane & 15;
    const int quad = lane >> 4;
    const long row0 = (long)blockIdx.x * MT;

    f32x4 acc[4][6];
#pragma unroll
    for (int mi = 0; mi < 4; ++mi)
#pragma unroll
        for (int ni = 0; ni < 6; ++ni) acc[mi][ni] = (f32x4)0.f;

    for (int kc = 0; kc < C / BK; ++kc) {
        const int k0 = kc * BK;
        __syncthreads();
        // stage X chunk [128][64] fp32 -> bf16 LDS (coalesced float4 reads)
#pragma unroll
        for (int i = 0; i < 8; ++i) {
            const int flat = tid + 256 * i;          // 0..2047
            const int r = flat >> 4, seg = flat & 15;
            const float4 xv = *(const float4*)(x + (row0 + r) * C + k0 + seg * 4);
            uint2 p; p.x = pack2(xv.x, xv.y); p.y = pack2(xv.z, xv.w);
            *(uint2*)&XL[r * ROWP + seg * 4] = p;
        }
        // stage Wt chunk [192][64] bf16 (16B copies)
#pragma unroll
        for (int i = 0; i < 6; ++i) {
            const int flat = tid + 256 * i;          // 0..1535
            const int n = flat >> 3, seg = flat & 7;
            const uint4 wv4 = *(const uint4*)(wt + n * C + k0 + seg * 8);
            *(uint4*)&WL[n * ROWP + seg * 8] = wv4;
        }
        __syncthreads();

#pragma unroll
        for (int s = 0; s < 2; ++s) {                // two K=32 steps per chunk
            const int kk = s * 32 + quad * 8;
            bf16x8 a[4], bfr[6];
#pragma unroll
            for (int mi = 0; mi < 4; ++mi)
                a[mi] = *(const bf16x8*)&XL[(wm * 64 + mi * 16 + l15) * ROWP + kk];
#pragma unroll
            for (int ni = 0; ni < 6; ++ni)
                bfr[ni] = *(const bf16x8*)&WL[(wn * 96 + ni * 16 + l15) * ROWP + kk];
#pragma unroll
            for (int mi = 0; mi < 4; ++mi)
#pragma unroll
                for (int ni = 0; ni < 6; ++ni)
                    acc[mi][ni] = __builtin_amdgcn_mfma_f32_16x16x32_bf16(
                        a[mi], bfr[ni], acc[mi][ni], 0, 0, 0);
        }
    }

    // epilogue: C/D layout col=lane&15, row=quad*4+reg (m89-verified)
#pragma unroll
    for (int mi = 0; mi < 4; ++mi) {
#pragma unroll
        for (int ni = 0; ni < 6; ++ni) {
            const int col   = wn * 96 + ni * 16 + l15;
            const int plane = col >> 6, dd = col & 63;
            float* op = qkv + (long)plane * PLANE;
            const long grow0 = row0 + wm * 64 + mi * 16 + quad * 4;
#pragma unroll
            for (int r = 0; r < 4; ++r)
                op[(grow0 + r) * HS + dd] = acc[mi][ni][r];
        }
    }
}

__global__ __launch_bounds__(256)
void attn_kernel(const float* __restrict__ qkv, float* __restrict__ out) {
    __shared__ float Ks[64 * HS];
    __shared__ float Vs[64 * HS];

    const int b = blockIdx.x;
    const int t = threadIdx.x;
    const int wave = t >> 6;

    const float* Q = qkv + 0 * PLANE + (long)b * T * HS;
    const float* K = qkv + 1 * PLANE + (long)b * T * HS;
    const float* V = qkv + 2 * PLANE + (long)b * T * HS;

    float q[HS];
#pragma unroll
    for (int d = 0; d < HS; d += 4) {
        const float4 v4 = *(const float4*)(Q + (long)t * HS + d);
        q[d] = v4.x; q[d + 1] = v4.y; q[d + 2] = v4.z; q[d + 3] = v4.w;
    }

    float o[HS];
#pragma unroll
    for (int d = 0; d < HS; ++d) o[d] = 0.f;
    float l = 0.f;

    for (int c = 0; c < 4; ++c) {
        __syncthreads();
        {
            const float4* ksrc = (const float4*)(K + (long)c * 64 * HS);
            const float4* vsrc = (const float4*)(V + (long)c * 64 * HS);
            float4* kdst = (float4*)Ks;
            float4* vdst = (float4*)Vs;
#pragma unroll
            for (int i = 0; i < 4; ++i) {
                kdst[t + i * 256] = ksrc[t + i * 256];
                vdst[t + i * 256] = vsrc[t + i * 256];
            }
        }
        __syncthreads();

        if (c <= wave) {
            const int jmax = min(64, t - c * 64 + 1);
            for (int j = 0; j < jmax; ++j) {
                float s = 0.f;
#pragma unroll
                for (int d = 0; d < HS; d += 4) {
                    const float4 kv = *(const float4*)(&Ks[j * HS + d]);
                    s += q[d] * kv.x + q[d + 1] * kv.y
                       + q[d + 2] * kv.z + q[d + 3] * kv.w;
                }
                const float p = __expf(s * SCALE);
                l += p;
#pragma unroll
                for (int d = 0; d < HS; d += 4) {
                    const float4 vv = *(const float4*)(&Vs[j * HS + d]);
                    o[d]     += p * vv.x;
                    o[d + 1] += p * vv.y;
                    o[d + 2] += p * vv.z;
                    o[d + 3] += p * vv.w;
                }
            }
        }
    }

    const float inv_l = 1.0f / l;
    float* op = out + ((long)b * T + t) * HS;
#pragma unroll
    for (int d = 0; d < HS; d += 4) {
        float4 v4;
        v4.x = o[d] * inv_l;  v4.y = o[d + 1] * inv_l;
        v4.z = o[d + 2] * inv_l;  v4.w = o[d + 3] * inv_l;
        *(float4*)(op + d) = v4;
    }
}

extern "C" void kernel_launch(void* const* d_in, const int* in_sizes, int n_in,
                              void* d_out, int out_size, void* d_ws, size_t ws_size,
                              hipStream_t stream) {
    const float* x = (const float*)d_in[0];      // [512,256,384]
    const float* w = (const float*)d_in[1];      // [384,192]
    float* out = (float*)d_out;                  // [512,256,64]
    float* qkv = (float*)d_ws;                   // 3 * PLANE floats = 96 MB
    short* wt  = (short*)((char*)d_ws + 3 * PLANE * sizeof(float)); // 144 KB

    wt_kernel<<<dim3((NT * C + 255) / 256), dim3(256), 0, stream>>>(w, wt);
    proj_kernel<<<dim3((unsigned)(BT / MT)), dim3(256), 0, stream>>>(x, wt, qkv);
    attn_kernel<<<dim3(B), dim3(T), 0, stream>>>(qkv, out);
}

// Round 4
// 323.488 us; speedup vs baseline: 2.8716x; 1.8224x over previous
//
#include <hip/hip_runtime.h>
#include <hip/hip_bf16.h>

// Single-head causal attention: x[512,256,384] fp32, w_qkv[384,192] fp32
//   qkv = x @ w_qkv ; out = softmax_causal(q k^T / sqrt(384)) @ v -> [512,256,64] fp32
//
// Round 4: all-f16 MFMA path (Round 3 + cvt_pkrtz type fix).
//   wt_kernel  : pack W^T -> f16 [192][384]
//   proj_kernel: 128x192 MFMA GEMM (16x16x32_f16), cvt_pkrtz staging,
//                writes Q,K as f16 [b][t][64] and V TRANSPOSED f16 [b][64][256]
//   attn_kernel: flash-style. S^T = K.Q^T via 16x16x32_f16 -> C-layout of S^T
//                IS the B-operand layout of 16x16x16f16 -> P.V with zero
//                LDS transform. V^T staged in LDS; no barriers in chunk loop.

constexpr int B  = 512;
constexpr int T  = 256;
constexpr int C  = 384;
constexpr int HS = 64;
constexpr long BT = (long)B * T;     // 131072
constexpr long PLANE = BT * HS;      // 8,388,608 elems per plane
constexpr float SCALE = 0.05103103630798288f; // 1/sqrt(384)

constexpr int NT   = 192;
constexpr int MT   = 128;
constexpr int BK   = 64;
constexpr int ROWP = 72;    // proj LDS pitch (f16): 144 B/row -> 2-way banks (free)
constexpr int VP   = 264;   // attn V^T LDS pitch: 528 B/row, 16B-aligned rows

typedef _Float16 f16x8 __attribute__((ext_vector_type(8)));
typedef _Float16 f16x4 __attribute__((ext_vector_type(4)));
typedef __fp16   fp16x2_raw __attribute__((ext_vector_type(2)));  // cvt_pkrtz return type
typedef float    f32x4 __attribute__((ext_vector_type(4)));

__global__ __launch_bounds__(256)
void wt_kernel(const float* __restrict__ w, _Float16* __restrict__ wt) {
    const int idx = blockIdx.x * 256 + threadIdx.x;
    if (idx < NT * C) {
        const int n = idx / C, k = idx % C;
        wt[idx] = (_Float16)w[k * NT + n];       // wt[n][k] = w[k][n]
    }
}

__global__ __launch_bounds__(256)
void proj_kernel(const float* __restrict__ x, const _Float16* __restrict__ wt,
                 _Float16* __restrict__ qp, _Float16* __restrict__ kp,
                 _Float16* __restrict__ vtp) {
    __shared__ __align__(16) _Float16 XL[MT * ROWP];   // 18.4 KB
    __shared__ __align__(16) _Float16 WL[NT * ROWP];   // 27.6 KB

    const int tid  = threadIdx.x;
    const int lane = tid & 63;
    const int wv   = tid >> 6;
    const int wm   = wv >> 1, wn = wv & 1;
    const int l15  = lane & 15, quad = lane >> 4;
    const long row0 = (long)blockIdx.x * MT;

    f32x4 acc[4][6];
#pragma unroll
    for (int mi = 0; mi < 4; ++mi)
#pragma unroll
        for (int ni = 0; ni < 6; ++ni) acc[mi][ni] = (f32x4)0.f;

    for (int kc = 0; kc < C / BK; ++kc) {
        const int k0 = kc * BK;
        __syncthreads();
#pragma unroll
        for (int i = 0; i < 8; ++i) {
            const int flat = tid + 256 * i;      // 0..2047
            const int r = flat >> 4, seg = flat & 15;
            const float4 xv = *(const float4*)(x + (row0 + r) * C + k0 + seg * 4);
            union { fp16x2_raw h[2]; uint2 u; } cvt;
            cvt.h[0] = __builtin_amdgcn_cvt_pkrtz(xv.x, xv.y);
            cvt.h[1] = __builtin_amdgcn_cvt_pkrtz(xv.z, xv.w);
            *(uint2*)&XL[r * ROWP + seg * 4] = cvt.u;
        }
#pragma unroll
        for (int i = 0; i < 6; ++i) {
            const int flat = tid + 256 * i;      // 0..1535
            const int n = flat >> 3, seg = flat & 7;
            *(uint4*)&WL[n * ROWP + seg * 8] = *(const uint4*)(wt + n * C + k0 + seg * 8);
        }
        __syncthreads();

#pragma unroll
        for (int s = 0; s < 2; ++s) {
            const int kk = s * 32 + quad * 8;
            f16x8 a[4], bfr[6];
#pragma unroll
            for (int mi = 0; mi < 4; ++mi)
                a[mi] = *(const f16x8*)&XL[(wm * 64 + mi * 16 + l15) * ROWP + kk];
#pragma unroll
            for (int ni = 0; ni < 6; ++ni)
                bfr[ni] = *(const f16x8*)&WL[(wn * 96 + ni * 16 + l15) * ROWP + kk];
#pragma unroll
            for (int mi = 0; mi < 4; ++mi)
#pragma unroll
                for (int ni = 0; ni < 6; ++ni)
                    acc[mi][ni] = __builtin_amdgcn_mfma_f32_16x16x32_f16(
                        a[mi], bfr[ni], acc[mi][ni], 0, 0, 0);
        }
    }

    // epilogue: C/D layout col=lane&15, row=quad*4+reg
#pragma unroll
    for (int mi = 0; mi < 4; ++mi) {
        const long grow0 = row0 + wm * 64 + mi * 16 + quad * 4;
        const int bb = (int)(grow0 >> 8);        // batch (block never crosses)
        const int t0 = (int)(grow0 & 255);
#pragma unroll
        for (int ni = 0; ni < 6; ++ni) {
            const int colbase = wn * 96 + ni * 16;
            const int col = colbase + l15;
            if (colbase < 64) {                  // Q plane [b][t][64]
#pragma unroll
                for (int r = 0; r < 4; ++r)
                    qp[(grow0 + r) * HS + col] = (_Float16)acc[mi][ni][r];
            } else if (colbase < 128) {          // K plane [b][t][64]
#pragma unroll
                for (int r = 0; r < 4; ++r)
                    kp[(grow0 + r) * HS + (col - 64)] = (_Float16)acc[mi][ni][r];
            } else {                             // V^T plane [b][64][256]
                f16x4 pv;
#pragma unroll
                for (int r = 0; r < 4; ++r) pv[r] = (_Float16)acc[mi][ni][r];
                *(f16x4*)&vtp[(long)bb * (HS * T) + (col - 128) * T + t0] = pv;
            }
        }
    }
}

__global__ __launch_bounds__(256)
void attn_kernel(const _Float16* __restrict__ qp, const _Float16* __restrict__ kp,
                 const _Float16* __restrict__ vtp, float* __restrict__ out) {
    __shared__ __align__(16) _Float16 VL[HS * VP];   // 33 KB -> 2+ blocks/CU

    const int b = blockIdx.x, tid = threadIdx.x;
    const int lane = tid & 63, w = tid >> 6;     // wave w: queries [w*64, w*64+64)
    const int l15 = lane & 15, quad = lane >> 4;

    // stage V^T [64][256] -> LDS (coalesced 16B)
    const _Float16* Vg = vtp + (long)b * (HS * T);
#pragma unroll
    for (int i = 0; i < 8; ++i) {
        const int flat = tid + 256 * i;          // 0..2047
        const int r = flat >> 5, seg = flat & 31;
        *(uint4*)&VL[r * VP + seg * 8] = *(const uint4*)(Vg + r * T + seg * 8);
    }
    __syncthreads();

    // Q B-operand frags (persist; direct from global, 64B segments)
    const _Float16* Qg = qp + ((long)b * T + w * 64) * HS;
    const _Float16* Kg = kp + (long)b * T * HS;
    f16x8 qf[4][2];
#pragma unroll
    for (int ni = 0; ni < 4; ++ni)
#pragma unroll
        for (int ks = 0; ks < 2; ++ks)
            qf[ni][ks] = *(const f16x8*)(Qg + (ni * 16 + l15) * HS + ks * 32 + quad * 8);

    f32x4 o[4][4];                               // O^T frags [di][ni]
#pragma unroll
    for (int di = 0; di < 4; ++di)
#pragma unroll
        for (int ni = 0; ni < 4; ++ni) o[di][ni] = (f32x4)0.f;
    float lp[4] = {0.f, 0.f, 0.f, 0.f};          // per-q denominators (partial)

    for (int c = 0; c <= w; ++c) {               // wave-uniform trip count
        const bool diag = (c == w);
#pragma unroll
        for (int kt = 0; kt < 4; ++kt) {
            const int key0 = c * 64 + kt * 16;
            // K A-frags from global (rows l15, 64B segments)
            const f16x8 ka0 = *(const f16x8*)(Kg + (key0 + l15) * HS + quad * 8);
            const f16x8 ka1 = *(const f16x8*)(Kg + (key0 + l15) * HS + 32 + quad * 8);
            // V^T A-frags from LDS (K=16 each)
            f16x4 va[4];
#pragma unroll
            for (int di = 0; di < 4; ++di)
                va[di] = *(const f16x4*)&VL[(di * 16 + l15) * VP + key0 + quad * 4];
#pragma unroll
            for (int ni = 0; ni < 4; ++ni) {
                if (diag && kt > ni) continue;   // fully-masked tile
                // S^T tile: D[m=key][n=q]; lane holds q=l15, keys=quad*4+r
                f32x4 s = {0.f, 0.f, 0.f, 0.f};
                s = __builtin_amdgcn_mfma_f32_16x16x32_f16(ka0, qf[ni][0], s, 0, 0, 0);
                s = __builtin_amdgcn_mfma_f32_16x16x32_f16(ka1, qf[ni][1], s, 0, 0, 0);
                const bool dmask = diag && (kt == ni);
                f16x4 pb;                        // = B-operand frag for 16x16x16
                float psum = 0.f;
#pragma unroll
                for (int r = 0; r < 4; ++r) {
                    float pr = __expf(s[r] * SCALE);   // logits*scale in ±4: no max-shift
                    pr = (dmask && (quad * 4 + r > l15)) ? 0.f : pr;
                    psum += pr;
                    pb[r] = (_Float16)pr;
                }
                lp[ni] += psum;
#pragma unroll
                for (int di = 0; di < 4; ++di)   // O^T[d][q] += V^T . P^T
                    o[di][ni] = __builtin_amdgcn_mfma_f32_16x16x16f16(
                        va[di], pb, o[di][ni], 0, 0, 0);
            }
        }
    }

    // reduce denominators across quads (lanes quad*16+l15 share q)
#pragma unroll
    for (int ni = 0; ni < 4; ++ni) {
        float v = lp[ni];
        v += __shfl_xor(v, 16, 64);
        v += __shfl_xor(v, 32, 64);
        lp[ni] = 1.0f / v;
    }

    // store: O^T frag lane holds q=l15 (col), d=di*16+quad*4+r -> float4 along d
    float* ob = out + ((long)b * T + w * 64) * HS;
#pragma unroll
    for (int ni = 0; ni < 4; ++ni)
#pragma unroll
        for (int di = 0; di < 4; ++di) {
            float4 val;
            val.x = o[di][ni][0] * lp[ni];
            val.y = o[di][ni][1] * lp[ni];
            val.z = o[di][ni][2] * lp[ni];
            val.w = o[di][ni][3] * lp[ni];
            *(float4*)&ob[(ni * 16 + l15) * HS + di * 16 + quad * 4] = val;
        }
}

extern "C" void kernel_launch(void* const* d_in, const int* in_sizes, int n_in,
                              void* d_out, int out_size, void* d_ws, size_t ws_size,
                              hipStream_t stream) {
    const float* x = (const float*)d_in[0];      // [512,256,384]
    const float* w = (const float*)d_in[1];      // [384,192]
    float* out = (float*)d_out;                  // [512,256,64] fp32

    _Float16* qp  = (_Float16*)d_ws;             // [B][T][64]
    _Float16* kp  = qp + PLANE;                  // [B][T][64]
    _Float16* vtp = kp + PLANE;                  // [B][64][T]  (transposed)
    _Float16* wt  = vtp + PLANE;                 // [192][384]

    wt_kernel<<<dim3((NT * C + 255) / 256), dim3(256), 0, stream>>>(w, wt);
    proj_kernel<<<dim3((unsigned)(BT / MT)), dim3(256), 0, stream>>>(x, wt, qp, kp, vtp);
    attn_kernel<<<dim3(B), dim3(256), 0, stream>>>(qp, kp, vtp, out);
}